// Round 1
// baseline (912.234 us; speedup 1.0000x reference)
//
#include <hip/hip_runtime.h>
#include <hip/hip_bf16.h>

#define D_MODEL 768
#define N_HEAD 12
#define D_HEAD 64
#define BATCH 4
#define SEQ 1024
#define HB (N_HEAD * BATCH)           // 48
#define PROJ_ELEMS (BATCH * SEQ * D_MODEL)   // 3,145,728
#define KT 16

// ---------------------------------------------------------------------------
// Kernel 1: QKV projection GEMM (fp32, 64x64 tile, 256 thr, 4x4 micro-tile)
// Y[m][n] = sum_k X[m][k] * W[n][k] + bias[n], written head-split:
// out[((h*4+b)*1024+l)*64 + dh], h=n>>6, dh=n&63, b=m>>10, l=m&1023
// ---------------------------------------------------------------------------
__global__ __launch_bounds__(256) void proj_gemm(
    const float* __restrict__ x0, const float* __restrict__ x1, const float* __restrict__ x2,
    const float* __restrict__ w0, const float* __restrict__ w1, const float* __restrict__ w2,
    const float* __restrict__ c0, const float* __restrict__ c1, const float* __restrict__ c2,
    float* __restrict__ out_base)
{
    const int z = blockIdx.z;
    const float* X  = (z == 0) ? x0 : (z == 1) ? x1 : x2;
    const float* W  = (z == 0) ? w0 : (z == 1) ? w1 : w2;
    const float* Bv = (z == 0) ? c0 : (z == 1) ? c1 : c2;
    float* Out = out_base + (size_t)z * PROJ_ELEMS;

    const int m0 = blockIdx.y * 64;      // over M = 4096
    const int n0 = blockIdx.x * 64;      // over N = 768
    const int K = D_MODEL;

    __shared__ float As[KT][64];
    __shared__ float Bs[KT][64];

    const int tid = threadIdx.x;
    const int tm = tid >> 4, tn = tid & 15;
    const int lr = tid >> 2;             // 0..63
    const int lc4 = (tid & 3) * 4;       // 0,4,8,12

    float acc[4][4] = {};

    for (int k0 = 0; k0 < K; k0 += KT) {
        float4 a4 = *(const float4*)(X + (size_t)(m0 + lr) * K + k0 + lc4);
        As[lc4 + 0][lr] = a4.x; As[lc4 + 1][lr] = a4.y;
        As[lc4 + 2][lr] = a4.z; As[lc4 + 3][lr] = a4.w;
        float4 b4 = *(const float4*)(W + (size_t)(n0 + lr) * K + k0 + lc4);
        Bs[lc4 + 0][lr] = b4.x; Bs[lc4 + 1][lr] = b4.y;
        Bs[lc4 + 2][lr] = b4.z; Bs[lc4 + 3][lr] = b4.w;
        __syncthreads();
        #pragma unroll
        for (int kk = 0; kk < KT; ++kk) {
            float a[4], b[4];
            #pragma unroll
            for (int i = 0; i < 4; ++i) a[i] = As[kk][tm * 4 + i];
            #pragma unroll
            for (int j = 0; j < 4; ++j) b[j] = Bs[kk][tn * 4 + j];
            #pragma unroll
            for (int i = 0; i < 4; ++i)
                #pragma unroll
                for (int j = 0; j < 4; ++j)
                    acc[i][j] += a[i] * b[j];
        }
        __syncthreads();
    }

    const int n = n0 + tn * 4;
    const int hh = n >> 6, dh = n & 63;
    #pragma unroll
    for (int i = 0; i < 4; ++i) {
        const int m = m0 + tm * 4 + i;
        const int bi = m >> 10, li = m & 1023;
        float4 r;
        r.x = acc[i][0] + Bv[n + 0];
        r.y = acc[i][1] + Bv[n + 1];
        r.z = acc[i][2] + Bv[n + 2];
        r.w = acc[i][3] + Bv[n + 3];
        *(float4*)(Out + ((size_t)((hh * BATCH + bi) * SEQ + li)) * D_HEAD + dh) = r;
    }
}

// ---------------------------------------------------------------------------
// Kernel 2: loc logits. For each (b,l,t): read 5 floats once, emit 12 heads'
// log(max(relu(dot5+b),1e-6)) (or -1e30 if masked) into fused[h][b][l][t].
// ---------------------------------------------------------------------------
__global__ __launch_bounds__(256) void loc_logits(
    const float* __restrict__ pl, const int* __restrict__ mask,
    const float* __restrict__ wloc, const float* __restrict__ bloc,
    float* __restrict__ fused)
{
    const int b = blockIdx.z;
    const int l = blockIdx.y;
    const int tc = blockIdx.x;       // t-chunk of 256
    const int tid = threadIdx.x;

    __shared__ float spl[256 * 5];
    __shared__ float swl[N_HEAD * 5];
    __shared__ float sbl[N_HEAD];
    if (tid < N_HEAD * 5) swl[tid] = wloc[tid];
    if (tid < N_HEAD) sbl[tid] = bloc[tid];

    const float* base = pl + (((size_t)b * SEQ + l) * SEQ + tc * 256) * 5;
    for (int i = tid; i < 256 * 5; i += 256) spl[i] = base[i];
    __syncthreads();

    const int t = tc * 256 + tid;
    const bool mk = mask[b * SEQ + t] != 0;
    const float p0 = spl[tid * 5 + 0], p1 = spl[tid * 5 + 1], p2 = spl[tid * 5 + 2];
    const float p3 = spl[tid * 5 + 3], p4 = spl[tid * 5 + 4];

    #pragma unroll
    for (int h = 0; h < N_HEAD; ++h) {
        float r = swl[h * 5 + 0] * p0 + swl[h * 5 + 1] * p1 + swl[h * 5 + 2] * p2 +
                  swl[h * 5 + 3] * p3 + swl[h * 5 + 4] * p4 + sbl[h];
        r = fmaxf(r, 0.f);
        float lt = mk ? -1e30f : __logf(fmaxf(r, 1e-6f));
        fused[((size_t)(h * BATCH + b) * SEQ + l) * SEQ + t] = lt;
    }
}

// ---------------------------------------------------------------------------
// Kernel 3: S[l][t] += scale * Q[l][:] . K[t][:]  per (h,b). K-dim = 64.
// ---------------------------------------------------------------------------
__global__ __launch_bounds__(256) void qk_gemm(
    const float* __restrict__ qh, const float* __restrict__ kh,
    float* __restrict__ fused)
{
    const int hb = blockIdx.z;
    const int m0 = blockIdx.y * 64;   // l
    const int n0 = blockIdx.x * 64;   // t
    const float* A = qh + (size_t)hb * SEQ * D_HEAD;
    const float* B = kh + (size_t)hb * SEQ * D_HEAD;
    float* C = fused + (size_t)hb * SEQ * SEQ;

    __shared__ float As[KT][64];
    __shared__ float Bs[KT][64];

    const int tid = threadIdx.x;
    const int tm = tid >> 4, tn = tid & 15;
    const int lr = tid >> 2;
    const int lc4 = (tid & 3) * 4;

    float acc[4][4] = {};

    for (int k0 = 0; k0 < D_HEAD; k0 += KT) {
        float4 a4 = *(const float4*)(A + (size_t)(m0 + lr) * D_HEAD + k0 + lc4);
        As[lc4 + 0][lr] = a4.x; As[lc4 + 1][lr] = a4.y;
        As[lc4 + 2][lr] = a4.z; As[lc4 + 3][lr] = a4.w;
        float4 b4 = *(const float4*)(B + (size_t)(n0 + lr) * D_HEAD + k0 + lc4);
        Bs[lc4 + 0][lr] = b4.x; Bs[lc4 + 1][lr] = b4.y;
        Bs[lc4 + 2][lr] = b4.z; Bs[lc4 + 3][lr] = b4.w;
        __syncthreads();
        #pragma unroll
        for (int kk = 0; kk < KT; ++kk) {
            float a[4], b[4];
            #pragma unroll
            for (int i = 0; i < 4; ++i) a[i] = As[kk][tm * 4 + i];
            #pragma unroll
            for (int j = 0; j < 4; ++j) b[j] = Bs[kk][tn * 4 + j];
            #pragma unroll
            for (int i = 0; i < 4; ++i)
                #pragma unroll
                for (int j = 0; j < 4; ++j)
                    acc[i][j] += a[i] * b[j];
        }
        __syncthreads();
    }

    const float scale = 0.125f;   // 1/sqrt(64)
    #pragma unroll
    for (int i = 0; i < 4; ++i) {
        const int m = m0 + tm * 4 + i;
        float* crow = C + (size_t)m * SEQ + n0 + tn * 4;
        float4 prior = *(float4*)crow;
        prior.x += scale * acc[i][0];
        prior.y += scale * acc[i][1];
        prior.z += scale * acc[i][2];
        prior.w += scale * acc[i][3];
        *(float4*)crow = prior;
    }
}

// ---------------------------------------------------------------------------
// Kernel 4: row softmax in place. One block per (hb,l) row of 1024.
// ---------------------------------------------------------------------------
__global__ __launch_bounds__(256) void softmax_k(float* __restrict__ fused)
{
    float* p = fused + (size_t)blockIdx.x * SEQ;
    const int tid = threadIdx.x;
    const int lane = tid & 63, wid = tid >> 6;
    __shared__ float sm[4], ss[4];

    float4 v = *(float4*)(p + tid * 4);
    float mx = fmaxf(fmaxf(v.x, v.y), fmaxf(v.z, v.w));
    #pragma unroll
    for (int o = 32; o > 0; o >>= 1) mx = fmaxf(mx, __shfl_down(mx, o, 64));
    if (lane == 0) sm[wid] = mx;
    __syncthreads();
    const float M = fmaxf(fmaxf(sm[0], sm[1]), fmaxf(sm[2], sm[3]));

    float4 e;
    e.x = __expf(v.x - M); e.y = __expf(v.y - M);
    e.z = __expf(v.z - M); e.w = __expf(v.w - M);
    float s = e.x + e.y + e.z + e.w;
    #pragma unroll
    for (int o = 32; o > 0; o >>= 1) s += __shfl_down(s, o, 64);
    if (lane == 0) ss[wid] = s;
    __syncthreads();
    const float S = ss[0] + ss[1] + ss[2] + ss[3];
    const float inv = 1.0f / S;

    e.x *= inv; e.y *= inv; e.z *= inv; e.w *= inv;
    *(float4*)(p + tid * 4) = e;
}

// ---------------------------------------------------------------------------
// Kernel 5: PV GEMM per (h,b): out[b][l][h*64+dh] = sum_t P[l][t] V[t][dh]
// ---------------------------------------------------------------------------
__global__ __launch_bounds__(256) void pv_gemm(
    const float* __restrict__ fused, const float* __restrict__ vh,
    float* __restrict__ attn_out)
{
    const int hb = blockIdx.z;
    const int h = hb >> 2, b = hb & 3;
    const int m0 = blockIdx.y * 64;   // l
    const float* A = fused + (size_t)hb * SEQ * SEQ;  // P[l][t]
    const float* B = vh + (size_t)hb * SEQ * D_HEAD;  // V[t][dh]

    __shared__ float As[KT][64];
    __shared__ float Bs[KT][64];

    const int tid = threadIdx.x;
    const int tm = tid >> 4, tn = tid & 15;
    const int lr = tid >> 2;
    const int lc4 = (tid & 3) * 4;
    const int kr = tid >> 4;            // 0..15
    const int nc4 = (tid & 15) * 4;     // 0..60

    float acc[4][4] = {};

    for (int k0 = 0; k0 < SEQ; k0 += KT) {
        float4 a4 = *(const float4*)(A + (size_t)(m0 + lr) * SEQ + k0 + lc4);
        As[lc4 + 0][lr] = a4.x; As[lc4 + 1][lr] = a4.y;
        As[lc4 + 2][lr] = a4.z; As[lc4 + 3][lr] = a4.w;
        float4 b4 = *(const float4*)(B + (size_t)(k0 + kr) * D_HEAD + nc4);
        *(float4*)&Bs[kr][nc4] = b4;
        __syncthreads();
        #pragma unroll
        for (int kk = 0; kk < KT; ++kk) {
            float a[4], bb[4];
            #pragma unroll
            for (int i = 0; i < 4; ++i) a[i] = As[kk][tm * 4 + i];
            #pragma unroll
            for (int j = 0; j < 4; ++j) bb[j] = Bs[kk][tn * 4 + j];
            #pragma unroll
            for (int i = 0; i < 4; ++i)
                #pragma unroll
                for (int j = 0; j < 4; ++j)
                    acc[i][j] += a[i] * bb[j];
        }
        __syncthreads();
    }

    #pragma unroll
    for (int i = 0; i < 4; ++i) {
        const int li = m0 + tm * 4 + i;
        float4 r;
        r.x = acc[i][0]; r.y = acc[i][1]; r.z = acc[i][2]; r.w = acc[i][3];
        *(float4*)(attn_out + ((size_t)b * SEQ + li) * D_MODEL + h * D_HEAD + tn * 4) = r;
    }
}

// ---------------------------------------------------------------------------
// Kernel 6: FC GEMM + bias + residual -> fc_out[m][n]
// ---------------------------------------------------------------------------
__global__ __launch_bounds__(256) void fc_gemm(
    const float* __restrict__ X, const float* __restrict__ W,
    const float* __restrict__ bias, const float* __restrict__ residual,
    float* __restrict__ Out)
{
    const int m0 = blockIdx.y * 64;
    const int n0 = blockIdx.x * 64;
    const int K = D_MODEL;

    __shared__ float As[KT][64];
    __shared__ float Bs[KT][64];

    const int tid = threadIdx.x;
    const int tm = tid >> 4, tn = tid & 15;
    const int lr = tid >> 2;
    const int lc4 = (tid & 3) * 4;

    float acc[4][4] = {};

    for (int k0 = 0; k0 < K; k0 += KT) {
        float4 a4 = *(const float4*)(X + (size_t)(m0 + lr) * K + k0 + lc4);
        As[lc4 + 0][lr] = a4.x; As[lc4 + 1][lr] = a4.y;
        As[lc4 + 2][lr] = a4.z; As[lc4 + 3][lr] = a4.w;
        float4 b4 = *(const float4*)(W + (size_t)(n0 + lr) * K + k0 + lc4);
        Bs[lc4 + 0][lr] = b4.x; Bs[lc4 + 1][lr] = b4.y;
        Bs[lc4 + 2][lr] = b4.z; Bs[lc4 + 3][lr] = b4.w;
        __syncthreads();
        #pragma unroll
        for (int kk = 0; kk < KT; ++kk) {
            float a[4], b[4];
            #pragma unroll
            for (int i = 0; i < 4; ++i) a[i] = As[kk][tm * 4 + i];
            #pragma unroll
            for (int j = 0; j < 4; ++j) b[j] = Bs[kk][tn * 4 + j];
            #pragma unroll
            for (int i = 0; i < 4; ++i)
                #pragma unroll
                for (int j = 0; j < 4; ++j)
                    acc[i][j] += a[i] * b[j];
        }
        __syncthreads();
    }

    const int n = n0 + tn * 4;
    #pragma unroll
    for (int i = 0; i < 4; ++i) {
        const int m = m0 + tm * 4 + i;
        const float* res = residual + (size_t)m * D_MODEL + n;
        float4 r;
        r.x = acc[i][0] + bias[n + 0] + res[0];
        r.y = acc[i][1] + bias[n + 1] + res[1];
        r.z = acc[i][2] + bias[n + 2] + res[2];
        r.w = acc[i][3] + bias[n + 3] + res[3];
        *(float4*)(Out + (size_t)m * D_MODEL + n) = r;
    }
}

// ---------------------------------------------------------------------------
// Kernel 7: LayerNorm over 768 per row -> d_out
// ---------------------------------------------------------------------------
__global__ __launch_bounds__(256) void ln_k(
    const float* __restrict__ X, const float* __restrict__ g,
    const float* __restrict__ bta, float* __restrict__ out)
{
    const int row = blockIdx.x;
    const float* x = X + (size_t)row * D_MODEL;
    const int tid = threadIdx.x;
    const int lane = tid & 63, wid = tid >> 6;
    __shared__ float s1[4], s2[4];

    float v0 = x[tid], v1 = x[tid + 256], v2 = x[tid + 512];
    float s = v0 + v1 + v2;
    float q = v0 * v0 + v1 * v1 + v2 * v2;
    #pragma unroll
    for (int o = 32; o > 0; o >>= 1) {
        s += __shfl_down(s, o, 64);
        q += __shfl_down(q, o, 64);
    }
    if (lane == 0) { s1[wid] = s; s2[wid] = q; }
    __syncthreads();
    const float sum = s1[0] + s1[1] + s1[2] + s1[3];
    const float sq  = s2[0] + s2[1] + s2[2] + s2[3];
    const float mu = sum * (1.0f / D_MODEL);
    const float var = sq * (1.0f / D_MODEL) - mu * mu;
    const float r = rsqrtf(var + 1e-5f);

    float* o = out + (size_t)row * D_MODEL;
    o[tid]       = (v0 - mu) * r * g[tid]       + bta[tid];
    o[tid + 256] = (v1 - mu) * r * g[tid + 256] + bta[tid + 256];
    o[tid + 512] = (v2 - mu) * r * g[tid + 512] + bta[tid + 512];
}

// ---------------------------------------------------------------------------
extern "C" void kernel_launch(void* const* d_in, const int* in_sizes, int n_in,
                              void* d_out, int out_size, void* d_ws, size_t ws_size,
                              hipStream_t stream)
{
    const float* q    = (const float*)d_in[0];
    const float* k    = (const float*)d_in[1];
    const float* v    = (const float*)d_in[2];
    const float* pl   = (const float*)d_in[3];
    const int*   mask = (const int*)d_in[4];
    const float* wq   = (const float*)d_in[5];
    const float* bq   = (const float*)d_in[6];
    const float* wk   = (const float*)d_in[7];
    const float* bk   = (const float*)d_in[8];
    const float* wv   = (const float*)d_in[9];
    const float* bv   = (const float*)d_in[10];
    const float* wfc  = (const float*)d_in[11];
    const float* bfc  = (const float*)d_in[12];
    const float* wloc = (const float*)d_in[13];
    const float* bloc = (const float*)d_in[14];
    const float* lng  = (const float*)d_in[15];
    const float* lnb  = (const float*)d_in[16];

    float* ws = (float*)d_ws;
    float* qh       = ws;                       // [h][b][l][64]
    float* kh       = ws + (size_t)PROJ_ELEMS;
    float* vh       = ws + (size_t)2 * PROJ_ELEMS;
    float* attn_out = ws + (size_t)3 * PROJ_ELEMS;   // [b][l][768]
    float* fc_out   = ws;                       // reuse qh (free after qk_gemm)

    float* out = (float*)d_out;                 // [b][l][768]
    float* fused = out + (size_t)PROJ_ELEMS;    // [h][b][l][t]

    proj_gemm<<<dim3(12, 64, 3), 256, 0, stream>>>(q, k, v, wq, wk, wv, bq, bk, bv, qh);
    loc_logits<<<dim3(4, SEQ, BATCH), 256, 0, stream>>>(pl, mask, wloc, bloc, fused);
    qk_gemm<<<dim3(16, 16, HB), 256, 0, stream>>>(qh, kh, fused);
    softmax_k<<<dim3(HB * SEQ), 256, 0, stream>>>(fused);
    pv_gemm<<<dim3(1, 16, HB), 256, 0, stream>>>(fused, vh, attn_out);
    fc_gemm<<<dim3(12, 64, 1), 256, 0, stream>>>(attn_out, wfc, bfc, q, fc_out);
    ln_k<<<dim3(BATCH * SEQ), 256, 0, stream>>>(fc_out, lng, lnb, out);
}

// Round 3
// 565.031 us; speedup vs baseline: 1.6145x; 1.6145x over previous
//
#include <hip/hip_runtime.h>
#include <hip/hip_bf16.h>
#include <stdint.h>

#define D_MODEL 768
#define N_HEAD 12
#define D_HEAD 64
#define BATCH 4
#define SEQ 1024
#define HB 48
#define PROJ_ELEMS (BATCH * SEQ * D_MODEL)   // 3145728

typedef __attribute__((ext_vector_type(8))) short bf8_t;   // 8 bf16 = one MFMA A/B frag
typedef __attribute__((ext_vector_type(4))) float f4_t;    // 4 fp32 = one MFMA C/D frag

__device__ inline unsigned short f2b(float f) {           // RNE float->bf16
    union { float f; unsigned u; } v; v.f = f;
    unsigned r = v.u + 0x7FFFu + ((v.u >> 16) & 1u);
    return (unsigned short)(r >> 16);
}

// ---------------------------------------------------------------------------
// fp32 -> bf16 bulk convert (z picks one of up to 4 tensors)
// ---------------------------------------------------------------------------
__global__ __launch_bounds__(256) void cvt_k(
    const float* __restrict__ s0, const float* __restrict__ s1,
    const float* __restrict__ s2, const float* __restrict__ s3,
    unsigned short* __restrict__ d0, unsigned short* __restrict__ d1,
    unsigned short* __restrict__ d2, unsigned short* __restrict__ d3, int n)
{
    const int z = blockIdx.z;
    const float* s = (z == 0) ? s0 : (z == 1) ? s1 : (z == 2) ? s2 : s3;
    unsigned short* d = (z == 0) ? d0 : (z == 1) ? d1 : (z == 2) ? d2 : d3;
    int i = (blockIdx.x * 256 + threadIdx.x) * 4;
    if (i >= n) return;
    float4 v = *(const float4*)(s + i);
    ushort4 o;
    o.x = f2b(v.x); o.y = f2b(v.y); o.z = f2b(v.z); o.w = f2b(v.w);
    *(ushort4*)(d + i) = o;
}

// ---------------------------------------------------------------------------
// QKV projection: Y = X * W^T + bias, bf16 MFMA, 128x128 tile, BK=64.
// Output head-split bf16: out[((h*4+b)*1024 + l)*64 + dh]
// ---------------------------------------------------------------------------
__global__ __launch_bounds__(256) void proj_mfma(
    const unsigned short* __restrict__ qb, const unsigned short* __restrict__ kb,
    const unsigned short* __restrict__ vb,
    const unsigned short* __restrict__ wqb, const unsigned short* __restrict__ wkb,
    const unsigned short* __restrict__ wvb,
    const float* __restrict__ bq, const float* __restrict__ bk, const float* __restrict__ bv,
    unsigned short* __restrict__ qh, unsigned short* __restrict__ kh,
    unsigned short* __restrict__ vh)
{
    const int z = blockIdx.z;
    const unsigned short* X = (z == 0) ? qb : (z == 1) ? kb : vb;
    const unsigned short* W = (z == 0) ? wqb : (z == 1) ? wkb : wvb;
    const float* bias = (z == 0) ? bq : (z == 1) ? bk : bv;
    unsigned short* Out = (z == 0) ? qh : (z == 1) ? kh : vh;

    const int m0 = blockIdx.y * 128;
    const int n0 = blockIdx.x * 128;

    __shared__ alignas(16) unsigned short As[128 * 72];   // row stride 72 shorts
    __shared__ alignas(16) unsigned short Bs[128 * 72];

    const int tid = threadIdx.x;
    const int wave = tid >> 6, lane = tid & 63;
    const int quad = lane >> 4, lq = lane & 15;
    const int wr = wave >> 1, wc = wave & 1;   // wave's 64x64 quadrant

    f4_t acc[4][4];
    #pragma unroll
    for (int i = 0; i < 4; ++i)
        #pragma unroll
        for (int j = 0; j < 4; ++j)
            #pragma unroll
            for (int r = 0; r < 4; ++r) acc[i][j][r] = 0.0f;

    for (int k0 = 0; k0 < D_MODEL; k0 += 64) {
        #pragma unroll
        for (int i = 0; i < 4; ++i) {
            int c = tid + 256 * i;            // 1024 16B-chunks per tile
            int row = c >> 3, off = (c & 7) * 8;
            *(bf8_t*)(As + row * 72 + off) =
                *(const bf8_t*)(X + (size_t)(m0 + row) * D_MODEL + k0 + off);
            *(bf8_t*)(Bs + row * 72 + off) =
                *(const bf8_t*)(W + (size_t)(n0 + row) * D_MODEL + k0 + off);
        }
        __syncthreads();
        #pragma unroll
        for (int ks = 0; ks < 2; ++ks) {
            bf8_t af[4], bfr[4];
            #pragma unroll
            for (int i = 0; i < 4; ++i)
                af[i] = *(const bf8_t*)(As + (wr * 64 + i * 16 + lq) * 72 + ks * 32 + quad * 8);
            #pragma unroll
            for (int j = 0; j < 4; ++j)
                bfr[j] = *(const bf8_t*)(Bs + (wc * 64 + j * 16 + lq) * 72 + ks * 32 + quad * 8);
            #pragma unroll
            for (int i = 0; i < 4; ++i)
                #pragma unroll
                for (int j = 0; j < 4; ++j)
                    acc[i][j] = __builtin_amdgcn_mfma_f32_16x16x32_bf16(af[i], bfr[j], acc[i][j], 0, 0, 0);
        }
        __syncthreads();
    }

    const int bb = m0 >> 10;
    #pragma unroll
    for (int j = 0; j < 4; ++j) {
        int col = n0 + wc * 64 + j * 16 + lq;
        float bv_ = bias[col];
        int h = col >> 6, dh = col & 63;
        #pragma unroll
        for (int i = 0; i < 4; ++i) {
            #pragma unroll
            for (int r = 0; r < 4; ++r) {
                int m = m0 + wr * 64 + i * 16 + quad * 4 + r;
                int l = m & 1023;
                Out[(((size_t)(h * BATCH + bb) * SEQ + l) << 6) + dh] = f2b(acc[i][j][r] + bv_);
            }
        }
    }
}

// ---------------------------------------------------------------------------
// Transpose V per (hb, t-tile): vT[hb][dh][t] from vh[hb][t][dh]
// ---------------------------------------------------------------------------
__global__ __launch_bounds__(256) void vtrans(
    const unsigned short* __restrict__ vh, unsigned short* __restrict__ vT)
{
    const int hb = blockIdx.y, tt = blockIdx.x;
    __shared__ alignas(16) unsigned short s[64 * 72];
    const int tid = threadIdx.x;
    #pragma unroll
    for (int i = 0; i < 2; ++i) {
        int c = tid + 256 * i;
        int t = c >> 3, off = (c & 7) * 8;
        *(bf8_t*)(s + t * 72 + off) =
            *(const bf8_t*)(vh + ((size_t)hb * SEQ + tt * 64 + t) * 64 + off);
    }
    __syncthreads();
    #pragma unroll
    for (int i = 0; i < 2; ++i) {
        int c = tid + 256 * i;
        int dh = c >> 3, toff = (c & 7) * 8;
        union { unsigned short u[8]; bf8_t v; } tmp;
        #pragma unroll
        for (int j = 0; j < 8; ++j) tmp.u[j] = s[(toff + j) * 72 + dh];
        *(bf8_t*)(vT + ((size_t)hb * 64 + dh) * SEQ + tt * 64 + toff) = tmp.v;
    }
}

// ---------------------------------------------------------------------------
// Fused loc + QK^T + mask -> raw logits in fused[h][b][l][t].
// Block: (b, l-tile 16, t-tile 64). Loops all 12 heads; pl read ONCE.
// 4 waves; wave w owns t-columns [w*16, w*16+16) of the tile.
// ---------------------------------------------------------------------------
__global__ __launch_bounds__(256) void attn_logits(
    const unsigned short* __restrict__ qh, const unsigned short* __restrict__ kh,
    const float* __restrict__ pl, const int* __restrict__ mask,
    const float* __restrict__ wloc, const float* __restrict__ bloc,
    float* __restrict__ fused)
{
    const int b = blockIdx.z;
    const int l0 = blockIdx.y * 16;
    const int t0 = blockIdx.x * 64;

    __shared__ alignas(16) float spl[16 * 324];            // [l][t*5], padded stride
    __shared__ alignas(16) unsigned short sq[16 * 72];
    __shared__ alignas(16) unsigned short sk[64 * 72];

    const int tid = threadIdx.x;
    {   // cooperative pl tile load: 16 rows x 320 floats = 1280 float4, 5/thread
        int r = tid >> 4, c16 = tid & 15;
        const float* src = pl + (((size_t)(b * SEQ + l0 + r) * SEQ) + t0) * 5;
        float* dst = spl + r * 324;
        #pragma unroll
        for (int j = 0; j < 5; ++j) {
            int f4i = j * 16 + c16;            // 0..79
            *(float4*)(dst + f4i * 4) = *(const float4*)(src + f4i * 4);
        }
    }
    const int wave = tid >> 6, lane = tid & 63;
    const int quad = lane >> 4, lq = lane & 15;
    const int mk = mask[b * SEQ + t0 + wave * 16 + lq];

    for (int h = 0; h < N_HEAD; ++h) {
        const int hb = h * BATCH + b;
        if (tid < 128) {   // stage Q: 16 rows x 8 chunks
            int row = tid >> 3, off = (tid & 7) * 8;
            *(bf8_t*)(sq + row * 72 + off) =
                *(const bf8_t*)(qh + (((size_t)hb * SEQ) + l0 + row) * 64 + off);
        }
        #pragma unroll
        for (int i = 0; i < 2; ++i) {          // stage K: 64 rows x 8 chunks
            int c = tid + 256 * i;
            int r2 = c >> 3, o2 = (c & 7) * 8;
            *(bf8_t*)(sk + r2 * 72 + o2) =
                *(const bf8_t*)(kh + (((size_t)hb * SEQ) + t0 + r2) * 64 + o2);
        }
        __syncthreads();

        const float wl0 = wloc[h * 5 + 0], wl1 = wloc[h * 5 + 1], wl2 = wloc[h * 5 + 2];
        const float wl3 = wloc[h * 5 + 3], wl4 = wloc[h * 5 + 4];
        const float bl = bloc[h];

        bf8_t a0 = *(const bf8_t*)(sq + lq * 72 + quad * 8);
        bf8_t a1 = *(const bf8_t*)(sq + lq * 72 + 32 + quad * 8);
        bf8_t b0 = *(const bf8_t*)(sk + (wave * 16 + lq) * 72 + quad * 8);
        bf8_t b1 = *(const bf8_t*)(sk + (wave * 16 + lq) * 72 + 32 + quad * 8);
        f4_t acc = {0.f, 0.f, 0.f, 0.f};
        acc = __builtin_amdgcn_mfma_f32_16x16x32_bf16(a0, b0, acc, 0, 0, 0);
        acc = __builtin_amdgcn_mfma_f32_16x16x32_bf16(a1, b1, acc, 0, 0, 0);

        const int tt = wave * 16 + lq;          // tile-local t (0..63)
        #pragma unroll
        for (int r = 0; r < 4; ++r) {
            int ll = quad * 4 + r;              // tile-local l (0..15)
            const float* p5 = spl + ll * 324 + tt * 5;
            float loc = fmaf(wl0, p5[0], fmaf(wl1, p5[1], fmaf(wl2, p5[2],
                        fmaf(wl3, p5[3], fmaf(wl4, p5[4], bl)))));
            loc = fmaxf(loc, 0.0f);
            float lg = mk ? -1e30f : (0.125f * acc[r] + __logf(fmaxf(loc, 1e-6f)));
            fused[((size_t)hb * SEQ + l0 + ll) * SEQ + t0 + tt] = lg;
        }
        __syncthreads();
    }
}

// ---------------------------------------------------------------------------
// Per-row softmax stats: stats[row] = (max, 1/sum_exp). One wave per row.
// ---------------------------------------------------------------------------
__global__ __launch_bounds__(256) void row_stats(
    const float* __restrict__ fused, float* __restrict__ stats)
{
    const int row = blockIdx.x * 4 + (threadIdx.x >> 6);
    const int lane = threadIdx.x & 63;
    const float* p = fused + (size_t)row * SEQ;
    float4 v[4];
    #pragma unroll
    for (int i = 0; i < 4; ++i) v[i] = *(const float4*)(p + (i * 64 + lane) * 4);
    float m = -1e30f;
    #pragma unroll
    for (int i = 0; i < 4; ++i)
        m = fmaxf(m, fmaxf(fmaxf(v[i].x, v[i].y), fmaxf(v[i].z, v[i].w)));
    #pragma unroll
    for (int o = 32; o > 0; o >>= 1) m = fmaxf(m, __shfl_xor(m, o, 64));
    float s = 0.f;
    #pragma unroll
    for (int i = 0; i < 4; ++i)
        s += __expf(v[i].x - m) + __expf(v[i].y - m) + __expf(v[i].z - m) + __expf(v[i].w - m);
    #pragma unroll
    for (int o = 32; o > 0; o >>= 1) s += __shfl_xor(s, o, 64);
    if (lane == 0) { stats[(size_t)row * 2] = m; stats[(size_t)row * 2 + 1] = 1.0f / s; }
}

// ---------------------------------------------------------------------------
// PV with fused normalization: p = exp(x-M)/S written BACK to fused (output),
// and p (bf16) @ V via MFMA -> attn_out fp32 [b][l][768].
// ---------------------------------------------------------------------------
__global__ __launch_bounds__(256) void pv_norm(
    float* __restrict__ fused, const unsigned short* __restrict__ vT,
    const float* __restrict__ stats, float* __restrict__ attn_out)
{
    const int hb = blockIdx.y;
    const int l0 = blockIdx.x * 64;
    const int h = hb >> 2, b = hb & 3;

    __shared__ alignas(16) unsigned short sp[64 * 72];
    __shared__ alignas(16) unsigned short sv[64 * 72];
    __shared__ alignas(16) float sst[128];

    const int tid = threadIdx.x;
    if (tid < 128) sst[tid] = stats[((size_t)hb * SEQ + l0) * 2 + tid];
    const int wave = tid >> 6, lane = tid & 63;
    const int quad = lane >> 4, lq = lane & 15;

    f4_t acc[4];
    #pragma unroll
    for (int c = 0; c < 4; ++c)
        #pragma unroll
        for (int r = 0; r < 4; ++r) acc[c][r] = 0.f;
    __syncthreads();

    for (int tt = 0; tt < 16; ++tt) {
        #pragma unroll
        for (int i = 0; i < 4; ++i) {
            int c = tid + 256 * i;             // 1024 float4 chunks
            int row = c >> 4, f4i = c & 15;
            float* gp = fused + ((size_t)hb * SEQ + l0 + row) * SEQ + tt * 64 + f4i * 4;
            float4 v = *(const float4*)gp;
            float M = sst[row * 2], invS = sst[row * 2 + 1];
            float4 pv;
            pv.x = __expf(v.x - M) * invS;
            pv.y = __expf(v.y - M) * invS;
            pv.z = __expf(v.z - M) * invS;
            pv.w = __expf(v.w - M) * invS;
            *(float4*)gp = pv;
            ushort4 pb;
            pb.x = f2b(pv.x); pb.y = f2b(pv.y); pb.z = f2b(pv.z); pb.w = f2b(pv.w);
            *(ushort4*)(sp + row * 72 + f4i * 4) = pb;
        }
        #pragma unroll
        for (int i = 0; i < 2; ++i) {
            int c = tid + 256 * i;
            int row = c >> 3, off = (c & 7) * 8;
            *(bf8_t*)(sv + row * 72 + off) =
                *(const bf8_t*)(vT + ((size_t)hb * 64 + row) * SEQ + tt * 64 + off);
        }
        __syncthreads();
        bf8_t af0 = *(const bf8_t*)(sp + (wave * 16 + lq) * 72 + quad * 8);
        bf8_t af1 = *(const bf8_t*)(sp + (wave * 16 + lq) * 72 + 32 + quad * 8);
        #pragma unroll
        for (int c = 0; c < 4; ++c) {
            bf8_t b0 = *(const bf8_t*)(sv + (c * 16 + lq) * 72 + quad * 8);
            bf8_t b1 = *(const bf8_t*)(sv + (c * 16 + lq) * 72 + 32 + quad * 8);
            acc[c] = __builtin_amdgcn_mfma_f32_16x16x32_bf16(af0, b0, acc[c], 0, 0, 0);
            acc[c] = __builtin_amdgcn_mfma_f32_16x16x32_bf16(af1, b1, acc[c], 0, 0, 0);
        }
        __syncthreads();
    }
    #pragma unroll
    for (int c = 0; c < 4; ++c)
        #pragma unroll
        for (int r = 0; r < 4; ++r) {
            int l = l0 + wave * 16 + quad * 4 + r;
            attn_out[((size_t)b * SEQ + l) * D_MODEL + h * 64 + c * 16 + lq] = acc[c][r];
        }
}

// ---------------------------------------------------------------------------
// FC: Out = X(fp32,cvt inline) * W^T + bias + residual -> fp32
// ---------------------------------------------------------------------------
__global__ __launch_bounds__(256) void fc_mfma(
    const float* __restrict__ X, const unsigned short* __restrict__ W,
    const float* __restrict__ bias, const float* __restrict__ residual,
    float* __restrict__ Out)
{
    const int m0 = blockIdx.y * 128;
    const int n0 = blockIdx.x * 128;

    __shared__ alignas(16) unsigned short As[128 * 72];
    __shared__ alignas(16) unsigned short Bs[128 * 72];

    const int tid = threadIdx.x;
    const int wave = tid >> 6, lane = tid & 63;
    const int quad = lane >> 4, lq = lane & 15;
    const int wr = wave >> 1, wc = wave & 1;

    f4_t acc[4][4];
    #pragma unroll
    for (int i = 0; i < 4; ++i)
        #pragma unroll
        for (int j = 0; j < 4; ++j)
            #pragma unroll
            for (int r = 0; r < 4; ++r) acc[i][j][r] = 0.0f;

    for (int k0 = 0; k0 < D_MODEL; k0 += 64) {
        #pragma unroll
        for (int i = 0; i < 4; ++i) {
            int c = tid + 256 * i;
            int row = c >> 3, off = (c & 7) * 8;
            const float* src = X + (size_t)(m0 + row) * D_MODEL + k0 + off;
            float4 u0 = *(const float4*)src;
            float4 u1 = *(const float4*)(src + 4);
            union { unsigned short u[8]; bf8_t v; } t;
            t.u[0] = f2b(u0.x); t.u[1] = f2b(u0.y); t.u[2] = f2b(u0.z); t.u[3] = f2b(u0.w);
            t.u[4] = f2b(u1.x); t.u[5] = f2b(u1.y); t.u[6] = f2b(u1.z); t.u[7] = f2b(u1.w);
            *(bf8_t*)(As + row * 72 + off) = t.v;
            *(bf8_t*)(Bs + row * 72 + off) =
                *(const bf8_t*)(W + (size_t)(n0 + row) * D_MODEL + k0 + off);
        }
        __syncthreads();
        #pragma unroll
        for (int ks = 0; ks < 2; ++ks) {
            bf8_t af[4], bfr[4];
            #pragma unroll
            for (int i = 0; i < 4; ++i)
                af[i] = *(const bf8_t*)(As + (wr * 64 + i * 16 + lq) * 72 + ks * 32 + quad * 8);
            #pragma unroll
            for (int j = 0; j < 4; ++j)
                bfr[j] = *(const bf8_t*)(Bs + (wc * 64 + j * 16 + lq) * 72 + ks * 32 + quad * 8);
            #pragma unroll
            for (int i = 0; i < 4; ++i)
                #pragma unroll
                for (int j = 0; j < 4; ++j)
                    acc[i][j] = __builtin_amdgcn_mfma_f32_16x16x32_bf16(af[i], bfr[j], acc[i][j], 0, 0, 0);
        }
        __syncthreads();
    }

    #pragma unroll
    for (int j = 0; j < 4; ++j) {
        int col = n0 + wc * 64 + j * 16 + lq;
        float bv_ = bias[col];
        #pragma unroll
        for (int i = 0; i < 4; ++i) {
            #pragma unroll
            for (int r = 0; r < 4; ++r) {
                int m = m0 + wr * 64 + i * 16 + quad * 4 + r;
                Out[(size_t)m * D_MODEL + col] =
                    acc[i][j][r] + bv_ + residual[(size_t)m * D_MODEL + col];
            }
        }
    }
}

// ---------------------------------------------------------------------------
// Kernel: LayerNorm over 768 per row -> d_out
// ---------------------------------------------------------------------------
__global__ __launch_bounds__(256) void ln_k(
    const float* __restrict__ X, const float* __restrict__ g,
    const float* __restrict__ bta, float* __restrict__ out)
{
    const int row = blockIdx.x;
    const float* x = X + (size_t)row * D_MODEL;
    const int tid = threadIdx.x;
    const int lane = tid & 63, wid = tid >> 6;
    __shared__ float s1[4], s2[4];

    float v0 = x[tid], v1 = x[tid + 256], v2 = x[tid + 512];
    float s = v0 + v1 + v2;
    float q = v0 * v0 + v1 * v1 + v2 * v2;
    #pragma unroll
    for (int o = 32; o > 0; o >>= 1) {
        s += __shfl_down(s, o, 64);
        q += __shfl_down(q, o, 64);
    }
    if (lane == 0) { s1[wid] = s; s2[wid] = q; }
    __syncthreads();
    const float sum = s1[0] + s1[1] + s1[2] + s1[3];
    const float sq  = s2[0] + s2[1] + s2[2] + s2[3];
    const float mu = sum * (1.0f / D_MODEL);
    const float var = sq * (1.0f / D_MODEL) - mu * mu;
    const float r = rsqrtf(var + 1e-5f);

    float* o = out + (size_t)row * D_MODEL;
    o[tid]       = (v0 - mu) * r * g[tid]       + bta[tid];
    o[tid + 256] = (v1 - mu) * r * g[tid + 256] + bta[tid + 256];
    o[tid + 512] = (v2 - mu) * r * g[tid + 512] + bta[tid + 512];
}

// ---------------------------------------------------------------------------
extern "C" void kernel_launch(void* const* d_in, const int* in_sizes, int n_in,
                              void* d_out, int out_size, void* d_ws, size_t ws_size,
                              hipStream_t stream)
{
    const float* q    = (const float*)d_in[0];
    const float* k    = (const float*)d_in[1];
    const float* v    = (const float*)d_in[2];
    const float* pl   = (const float*)d_in[3];
    const int*   mask = (const int*)d_in[4];
    const float* wq   = (const float*)d_in[5];
    const float* bq   = (const float*)d_in[6];
    const float* wk   = (const float*)d_in[7];
    const float* bk   = (const float*)d_in[8];
    const float* wv   = (const float*)d_in[9];
    const float* bv   = (const float*)d_in[10];
    const float* wfc  = (const float*)d_in[11];
    const float* bfc  = (const float*)d_in[12];
    const float* wloc = (const float*)d_in[13];
    const float* bloc = (const float*)d_in[14];
    const float* lng  = (const float*)d_in[15];
    const float* lnb  = (const float*)d_in[16];

    char* W8 = (char*)d_ws;
    const size_t SLOT = (size_t)PROJ_ELEMS * 2;            // 6291456 B per bf16 tensor
    unsigned short* qb   = (unsigned short*)(W8 + 0 * SLOT);
    unsigned short* kb   = (unsigned short*)(W8 + 1 * SLOT);
    unsigned short* vb   = (unsigned short*)(W8 + 2 * SLOT);
    unsigned short* qh   = (unsigned short*)(W8 + 3 * SLOT);
    unsigned short* kh   = (unsigned short*)(W8 + 4 * SLOT);
    unsigned short* vh   = (unsigned short*)(W8 + 5 * SLOT);
    unsigned short* vT   = (unsigned short*)(W8 + 6 * SLOT);
    unsigned short* wqb  = (unsigned short*)(W8 + 7 * SLOT);                  // 4 weight slots
    unsigned short* wkb  = (unsigned short*)(W8 + 7 * SLOT + 1179648);
    unsigned short* wvb  = (unsigned short*)(W8 + 7 * SLOT + 2 * 1179648);
    unsigned short* wfcb = (unsigned short*)(W8 + 7 * SLOT + 3 * 1179648);
    float* stats         = (float*)(W8 + 7 * SLOT + 4 * 1179648);             // 393216 B
    // overlays (sources dead by the time these are written):
    float* attn_out = (float*)(W8 + 0 * SLOT);   // over qb+kb  (dead after proj)
    float* fc_out   = (float*)(W8 + 2 * SLOT);   // over vb+qh  (dead after proj/attn_logits)

    float* out   = (float*)d_out;                 // [b][l][768]
    float* fused = out + (size_t)PROJ_ELEMS;      // [h][b][l][t] fp32

    cvt_k<<<dim3(3072, 1, 3), 256, 0, stream>>>(q, k, v, v, qb, kb, vb, vb, PROJ_ELEMS);
    cvt_k<<<dim3(576, 1, 4), 256, 0, stream>>>(wq, wk, wv, wfc, wqb, wkb, wvb, wfcb,
                                               D_MODEL * D_MODEL);
    proj_mfma<<<dim3(6, 32, 3), 256, 0, stream>>>(qb, kb, vb, wqb, wkb, wvb,
                                                  bq, bk, bv, qh, kh, vh);
    vtrans<<<dim3(16, HB), 256, 0, stream>>>(vh, vT);
    attn_logits<<<dim3(16, 64, BATCH), 256, 0, stream>>>(qh, kh, pl, mask, wloc, bloc, fused);
    row_stats<<<dim3(HB * SEQ / 4), 256, 0, stream>>>(fused, stats);
    pv_norm<<<dim3(16, HB), 256, 0, stream>>>(fused, vT, stats, attn_out);
    fc_mfma<<<dim3(6, 32), 256, 0, stream>>>(attn_out, wfcb, bfc, q, fc_out);
    ln_k<<<dim3(BATCH * SEQ), 256, 0, stream>>>(fc_out, lng, lnb, out);
}